// Round 1
// baseline (1678.132 us; speedup 1.0000x reference)
//
#include <hip/hip_runtime.h>

#define CCH 32
#define NPIX 65536
#define NVOX (128 * 128 * 64)

// feats[c][i] (C x N_PIX, row-major) -> feats_t[i][c] (N_PIX x C)
__global__ __launch_bounds__(256) void transpose_feats_k(
    const float* __restrict__ feats, float* __restrict__ feats_t)
{
    int gid = blockIdx.x * 256 + threadIdx.x;   // 0 .. C*NPIX-1
    int i = gid >> 5;
    int c = gid & 31;
    feats_t[gid] = feats[(size_t)c * NPIX + i]; // coalesced write, strided read (8 MB total)
}

// One 32-lane group per event; lane = channel. Atomic adds land in one
// contiguous 128B line per event in vol_t[v][c].
__global__ __launch_bounds__(256) void scatter_t_k(
    const float* __restrict__ feats_t,
    const int* __restrict__ vox_s, const int* __restrict__ vox_d,
    const int* __restrict__ idx_s, const int* __restrict__ idx_d,
    float* __restrict__ vol_t, int K)
{
    int c = threadIdx.x & 31;
    int g = (blockIdx.x * blockDim.x + threadIdx.x) >> 5;
    int gstride = (gridDim.x * blockDim.x) >> 5;
    int total = 2 * K;
    for (int e = g; e < total; e += gstride) {
        int v, i;
        if (e < K) { v = vox_s[e];     i = idx_s[e]; }
        else       { v = vox_d[e - K]; i = idx_d[e - K]; }
        float val = feats_t[((size_t)i << 5) + c];      // coalesced 128B gather
        atomicAdd(&vol_t[((size_t)v << 5) + c], val);   // contiguous 128B RMW
    }
}

// vol_t[v][c] -> out[c][v], 64-voxel x 32-channel tiles via LDS.
__global__ __launch_bounds__(256) void transpose_out_k(
    const float* __restrict__ vol_t, float* __restrict__ out)
{
    __shared__ float lds[64][33];
    int v0 = blockIdx.x * 64;
    int t = threadIdx.x;
#pragma unroll
    for (int p = 0; p < 8; ++p) {
        int u = p * 256 + t;                       // 0..2047
        lds[u >> 5][u & 31] = vol_t[(size_t)v0 * 32 + u];  // coalesced read
    }
    __syncthreads();
#pragma unroll
    for (int p = 0; p < 8; ++p) {
        int u = p * 256 + t;
        int c = u >> 6;       // 0..31
        int vv = u & 63;      // 0..63
        out[(size_t)c * NVOX + v0 + vv] = lds[vv][c];      // coalesced 256B rows
    }
}

// Fallback when workspace is too small: atomics straight into out[c][v].
__global__ __launch_bounds__(256) void scatter_direct_k(
    const float* __restrict__ feats,
    const int* __restrict__ vox_s, const int* __restrict__ vox_d,
    const int* __restrict__ idx_s, const int* __restrict__ idx_d,
    float* __restrict__ out, int K)
{
    int c = threadIdx.x & 31;
    int g = (blockIdx.x * blockDim.x + threadIdx.x) >> 5;
    int gstride = (gridDim.x * blockDim.x) >> 5;
    int total = 2 * K;
    for (int e = g; e < total; e += gstride) {
        int v, i;
        if (e < K) { v = vox_s[e];     i = idx_s[e]; }
        else       { v = vox_d[e - K]; i = idx_d[e - K]; }
        atomicAdd(&out[(size_t)c * NVOX + v], feats[(size_t)c * NPIX + i]);
    }
}

extern "C" void kernel_launch(void* const* d_in, const int* in_sizes, int n_in,
                              void* d_out, int out_size, void* d_ws, size_t ws_size,
                              hipStream_t stream)
{
    const float* feats = (const float*)d_in[0];
    const int* vox_s   = (const int*)d_in[1];
    const int* vox_d   = (const int*)d_in[2];
    const int* idx_s   = (const int*)d_in[3];
    const int* idx_d   = (const int*)d_in[4];
    const int  K       = in_sizes[1];
    float* out = (float*)d_out;

    const size_t vol_bytes   = (size_t)NVOX * CCH * sizeof(float); // 128 MiB
    const size_t feats_bytes = (size_t)CCH * NPIX * sizeof(float); // 8 MiB

    if (ws_size >= vol_bytes + feats_bytes) {
        float* vol_t   = (float*)d_ws;
        float* feats_t = (float*)((char*)d_ws + vol_bytes);
        hipMemsetAsync(d_ws, 0, vol_bytes, stream);
        transpose_feats_k<<<(CCH * NPIX) / 256, 256, 0, stream>>>(feats, feats_t);
        scatter_t_k<<<8192, 256, 0, stream>>>(feats_t, vox_s, vox_d, idx_s, idx_d, vol_t, K);
        transpose_out_k<<<NVOX / 64, 256, 0, stream>>>(vol_t, out);
    } else {
        hipMemsetAsync(d_out, 0, (size_t)out_size * sizeof(float), stream);
        scatter_direct_k<<<8192, 256, 0, stream>>>(feats, vox_s, vox_d, idx_s, idx_d, out, K);
    }
}